// Round 7
// baseline (1544.031 us; speedup 1.0000x reference)
//
#include <hip/hip_runtime.h>
#include <hip/hip_bf16.h>

#define DM 512
#define NH 8
#define DK 64
#define SEQ 512
#define NB 8
#define NL 6
#define DFF 2048
#define OUTD 1000
#define EMB_SCALE 22.627416997969522f
#define PE_C (-0.017988946039015984f)  // -ln(10000)/512

typedef __bf16 bf16x8 __attribute__((ext_vector_type(8)));
typedef __bf16 bf16x4 __attribute__((ext_vector_type(4)));
typedef float f32x4 __attribute__((ext_vector_type(4)));

__device__ __forceinline__ void load16_lds(const __bf16* g, __bf16* l) {
  __builtin_amdgcn_global_load_lds(
      (const __attribute__((address_space(1))) void*)g,
      (__attribute__((address_space(3))) void*)l, 16, 0, 0);
}

__device__ __forceinline__ float dot8(bf16x8 w, const float* a) {
  float s = 0.f;
#pragma unroll
  for (int j = 0; j < 8; ++j) s += (float)w[j] * a[j];
  return s;
}

// ---------------- embedding (PE computed inline, float) ----------------
__global__ __launch_bounds__(256) void embed_enc(const int* __restrict__ x,
                                                 const float* __restrict__ emb,
                                                 float* __restrict__ e,
                                                 __bf16* __restrict__ eb) {
  int idx = blockIdx.x * 256 + threadIdx.x;
  int d = idx & (DM - 1);
  int bs = idx >> 9;
  int s = bs & (SEQ - 1);
  int tok = x[bs];
  float div = __expf((float)(d & ~1) * PE_C);
  float arg = (float)s * div;
  float pe = (d & 1) ? cosf(arg) : sinf(arg);
  float v = emb[(size_t)tok * DM + d] * EMB_SCALE + pe;
  e[idx] = v;
  eb[idx] = (__bf16)v;
}

// ---------------- weight transpose fp32[K][N] -> bf16[N][K] ----------------
__global__ __launch_bounds__(256) void transpose_w(const float* __restrict__ W,
                                                   __bf16* __restrict__ WT,
                                                   int K, int N) {
  __shared__ float t[32][33];
  size_t off = (size_t)blockIdx.z * K * N;
  W += off; WT += off;
  int k0 = blockIdx.y * 32, n0 = blockIdx.x * 32;
  int tx = threadIdx.x & 7, ty = threadIdx.x >> 3;
  float4 v = *(const float4*)&W[(size_t)(k0 + ty) * N + n0 + tx * 4];
  t[ty][tx * 4 + 0] = v.x; t[ty][tx * 4 + 1] = v.y;
  t[ty][tx * 4 + 2] = v.z; t[ty][tx * 4 + 3] = v.w;
  __syncthreads();
  bf16x4 o;
  o[0] = (__bf16)t[tx * 4 + 0][ty];
  o[1] = (__bf16)t[tx * 4 + 1][ty];
  o[2] = (__bf16)t[tx * 4 + 2][ty];
  o[3] = (__bf16)t[tx * 4 + 3][ty];
  *(bf16x4*)&WT[(size_t)(n0 + ty) * K + k0 + tx * 4] = o;
}

// ---------------- MFMA GEMM (global_load_lds staging, swizzled LDS) --------
template <int BN, bool RELU, bool WF32, bool WBF16, bool TRV, bool KVM>
__global__ __launch_bounds__(256) void mfma_gemm(
    const __bf16* __restrict__ A, const __bf16* __restrict__ BT,
    const float* __restrict__ bias, float* __restrict__ C,
    __bf16* __restrict__ Cb, __bf16* __restrict__ Vt, int M, int N, int K,
    long btStride, long bStride, long cStride) {
  int z = blockIdx.z;
  if (KVM) {
    long idx = (long)(z >> 1) * 3 + 1 + (z & 1);
    BT += idx * btStride;
    bias += idx * bStride;
  } else {
    BT += (size_t)z * btStride;
    bias += (size_t)z * bStride;
  }
  if (WF32) C += (size_t)z * cStride;
  if (WBF16) Cb += (size_t)z * cStride;

  constexpr int NI = BN / 32;
  __shared__ __bf16 As[128 * 64];
  __shared__ __bf16 Bs[BN * 64];

  int tid = threadIdx.x;
  int wave = tid >> 6, lane = tid & 63;
  int wm = wave >> 1, wn = wave & 1;
  int quad = lane >> 4, l16 = lane & 15;
  int rlane = lane >> 3, c8 = lane & 7;
  int m0 = blockIdx.y * 128, n0 = blockIdx.x * BN;
  int gcol = ((c8 ^ rlane) * 8);

  f32x4 acc[4][NI];
#pragma unroll
  for (int i = 0; i < 4; ++i)
#pragma unroll
    for (int j = 0; j < NI; ++j) acc[i][j] = (f32x4){0.f, 0.f, 0.f, 0.f};

  for (int k0 = 0; k0 < K; k0 += 64) {
    __syncthreads();
#pragma unroll
    for (int j = 0; j < 4; ++j) {
      int row = j * 32 + wave * 8 + rlane;
      load16_lds(&A[(size_t)(m0 + row) * K + k0 + gcol],
                 &As[(j * 32 + wave * 8) * 64]);
    }
#pragma unroll
    for (int j = 0; j < BN / 32; ++j) {
      int row = j * 32 + wave * 8 + rlane;
      load16_lds(&BT[(size_t)(n0 + row) * K + k0 + gcol],
                 &Bs[(j * 32 + wave * 8) * 64]);
    }
    __syncthreads();
#pragma unroll
    for (int kk = 0; kk < 64; kk += 32) {
      bf16x8 af[4], bf[NI];
#pragma unroll
      for (int i = 0; i < 4; ++i) {
        int row = wm * 64 + i * 16 + l16;
        af[i] = *(const bf16x8*)&As[row * 64 + ((((kk >> 3) + quad) ^ (row & 7)) * 8)];
      }
#pragma unroll
      for (int i = 0; i < NI; ++i) {
        int row = wn * (BN / 2) + i * 16 + l16;
        bf[i] = *(const bf16x8*)&Bs[row * 64 + ((((kk >> 3) + quad) ^ (row & 7)) * 8)];
      }
#pragma unroll
      for (int mi = 0; mi < 4; ++mi)
#pragma unroll
        for (int ni = 0; ni < NI; ++ni)
          acc[mi][ni] = __builtin_amdgcn_mfma_f32_16x16x32_bf16(
              af[mi], bf[ni], acc[mi][ni], 0, 0, 0);
    }
  }

#pragma unroll
  for (int ni = 0; ni < NI; ++ni) {
    int col = n0 + wn * (BN / 2) + ni * 16 + l16;
    float bv = bias[col];
    if (TRV && z == 2) {
      int b = m0 >> 9;
#pragma unroll
      for (int mi = 0; mi < 4; ++mi) {
        int srow = (m0 & 511) + wm * 64 + mi * 16 + quad * 4;
        bf16x4 pk;
#pragma unroll
        for (int r = 0; r < 4; ++r) pk[r] = (__bf16)(acc[mi][ni][r] + bv);
        *(bf16x4*)&Vt[((size_t)(b * 512 + col)) * 512 + srow] = pk;
      }
    } else {
#pragma unroll
      for (int mi = 0; mi < 4; ++mi) {
#pragma unroll
        for (int r = 0; r < 4; ++r) {
          int row = m0 + wm * 64 + mi * 16 + quad * 4 + r;
          float v = acc[mi][ni][r] + bv;
          if (RELU) v = fmaxf(v, 0.f);
          if (WF32) C[(size_t)row * N + col] = v;
          if (WBF16) Cb[(size_t)row * N + col] = (__bf16)v;
        }
      }
    }
  }
}

// ---------------- MFMA encoder attention (K natural, V pre-transposed) -----
#define SCP 520
__global__ __launch_bounds__(256) void attn_mfma(const __bf16* __restrict__ QKV,
                                                 const __bf16* __restrict__ Vt,
                                                 float* __restrict__ O) {
  __shared__ __bf16 Sc[16 * SCP];
  __shared__ __bf16 Tt[64 * 64];

  const long ACTL = (long)NB * SEQ * DM;
  int tid = threadIdx.x;
  int wave = tid >> 6, lane = tid & 63;
  int quad = lane >> 4, l16 = lane & 15;
  int rlane = lane >> 3, c8 = lane & 7;
  int q0 = blockIdx.x * 16;
  int bh = blockIdx.y, b = bh >> 3, h = bh & 7;
  const __bf16* Q = QKV;
  const __bf16* Kp = QKV + ACTL;
  size_t baseQ = ((size_t)b * SEQ + q0) * DM + h * DK;
  size_t baseK = ((size_t)b * SEQ) * DM + h * DK;
  const __bf16* VtB = Vt + ((size_t)(b * 512 + h * 64)) * 512;
  int gcol = (c8 ^ rlane) * 8;

  bf16x8 af0 = *(const bf16x8*)&Q[baseQ + (size_t)l16 * DM + quad * 8];
  bf16x8 af1 = *(const bf16x8*)&Q[baseQ + (size_t)l16 * DM + 32 + quad * 8];

  for (int kt = 0; kt < 8; ++kt) {
    __syncthreads();
#pragma unroll
    for (int j = 0; j < 2; ++j) {
      int row = j * 32 + wave * 8 + rlane;
      load16_lds(&Kp[baseK + (size_t)(kt * 64 + row) * DM + gcol],
                 &Tt[(j * 32 + wave * 8) * 64]);
    }
    __syncthreads();
    f32x4 acc = (f32x4){0.f, 0.f, 0.f, 0.f};
    int krow = wave * 16 + l16, sw = krow & 7;
    bf16x8 b0 = *(const bf16x8*)&Tt[krow * 64 + ((quad ^ sw) * 8)];
    bf16x8 b1 = *(const bf16x8*)&Tt[krow * 64 + (((4 + quad) ^ sw) * 8)];
    acc = __builtin_amdgcn_mfma_f32_16x16x32_bf16(af0, b0, acc, 0, 0, 0);
    acc = __builtin_amdgcn_mfma_f32_16x16x32_bf16(af1, b1, acc, 0, 0, 0);
#pragma unroll
    for (int r = 0; r < 4; ++r)
      Sc[(quad * 4 + r) * SCP + kt * 64 + wave * 16 + l16] =
          (__bf16)(acc[r] * 0.125f);
  }
  __syncthreads();

#pragma unroll
  for (int rr = 0; rr < 4; ++rr) {
    int r = wave * 4 + rr;
    float v[8];
    float mx = -1e30f;
#pragma unroll
    for (int j = 0; j < 8; ++j) {
      v[j] = (float)Sc[r * SCP + j * 64 + lane];
      mx = fmaxf(mx, v[j]);
    }
    for (int o = 32; o > 0; o >>= 1) mx = fmaxf(mx, __shfl_xor(mx, o));
    float sum = 0.f;
#pragma unroll
    for (int j = 0; j < 8; ++j) { v[j] = __expf(v[j] - mx); sum += v[j]; }
    for (int o = 32; o > 0; o >>= 1) sum += __shfl_xor(sum, o);
    float inv = 1.f / sum;
#pragma unroll
    for (int j = 0; j < 8; ++j)
      Sc[r * SCP + j * 64 + lane] = (__bf16)(v[j] * inv);
  }

  f32x4 oacc = (f32x4){0.f, 0.f, 0.f, 0.f};
  for (int kt = 0; kt < 8; ++kt) {
    __syncthreads();
#pragma unroll
    for (int j = 0; j < 2; ++j) {
      int row = j * 32 + wave * 8 + rlane;
      load16_lds(&VtB[(size_t)row * 512 + kt * 64 + gcol],
                 &Tt[(j * 32 + wave * 8) * 64]);
    }
    __syncthreads();
    int drow = wave * 16 + l16, sw = drow & 7;
#pragma unroll
    for (int kk = 0; kk < 64; kk += 32) {
      bf16x8 pa = *(const bf16x8*)&Sc[l16 * SCP + kt * 64 + kk + quad * 8];
      bf16x8 vb = *(const bf16x8*)&Tt[drow * 64 + ((((kk >> 3) + quad) ^ sw) * 8)];
      oacc = __builtin_amdgcn_mfma_f32_16x16x32_bf16(pa, vb, oacc, 0, 0, 0);
    }
  }
#pragma unroll
  for (int r = 0; r < 4; ++r)
    O[((size_t)b * SEQ + q0 + quad * 4 + r) * DM + h * DK + wave * 16 + l16] =
        oacc[r];
}

// ---------------- residual + layernorm (encoder) ----------------
template <bool WB>
__global__ __launch_bounds__(256) void add_ln(
    const float* __restrict__ x, const float* __restrict__ res,
    const float* __restrict__ g, const float* __restrict__ beta,
    float* __restrict__ y, __bf16* __restrict__ yb) {
  int row = blockIdx.x;
  int tid = threadIdx.x;
  const float* xr = x + (size_t)row * DM;
  const float* rr = res + (size_t)row * DM;
  float v0 = xr[tid] + rr[tid];
  float v1 = xr[tid + 256] + rr[tid + 256];
  float s = v0 + v1, sq = v0 * v0 + v1 * v1;
  for (int o = 32; o > 0; o >>= 1) {
    s += __shfl_xor(s, o);
    sq += __shfl_xor(sq, o);
  }
  __shared__ float ps[4], pq[4];
  int wv = tid >> 6;
  if ((tid & 63) == 0) { ps[wv] = s; pq[wv] = sq; }
  __syncthreads();
  s = ps[0] + ps[1] + ps[2] + ps[3];
  sq = pq[0] + pq[1] + pq[2] + pq[3];
  float mean = s * (1.f / DM);
  float var = sq * (1.f / DM) - mean * mean;
  float rstd = rsqrtf(var + 1e-5f);
  float o0 = (v0 - mean) * rstd * g[tid] + beta[tid];
  float o1 = (v1 - mean) * rstd * g[tid + 256] + beta[tid + 256];
  y[(size_t)row * DM + tid] = o0;
  y[(size_t)row * DM + tid + 256] = o1;
  if (WB) {
    yb[(size_t)row * DM + tid] = (__bf16)o0;
    yb[(size_t)row * DM + tid + 256] = (__bf16)o1;
  }
}

// ============ persistent decoder mega-kernel ============
#define DBLK 64
#define WQS_ 262144L
#define WFS_ 1048576L
#define ACTL_ 2097152L

__device__ __forceinline__ void gridbar(unsigned* cnt, unsigned target) {
  __syncthreads();
  if (threadIdx.x == 0) {
    __threadfence();
    __hip_atomic_fetch_add(cnt, 1u, __ATOMIC_RELEASE, __HIP_MEMORY_SCOPE_AGENT);
    while (__hip_atomic_load(cnt, __ATOMIC_ACQUIRE, __HIP_MEMORY_SCOPE_AGENT) <
           target)
      __builtin_amdgcn_s_sleep(2);
    __threadfence();
  }
  __syncthreads();
}

// 256-thread row LN: y = LN(x + res), in-place-safe when y == res
__device__ __forceinline__ void ln_row256(const float* __restrict__ x,
                                          const float* __restrict__ res,
                                          const float* __restrict__ g,
                                          const float* __restrict__ beta,
                                          float* __restrict__ y) {
  __shared__ float ps[4], pq[4];
  int tid = threadIdx.x;
  float v0 = x[tid] + res[tid];
  float v1 = x[tid + 256] + res[tid + 256];
  float s = v0 + v1, sq = v0 * v0 + v1 * v1;
  for (int o = 32; o > 0; o >>= 1) {
    s += __shfl_xor(s, o);
    sq += __shfl_xor(sq, o);
  }
  int wv = tid >> 6;
  if ((tid & 63) == 0) { ps[wv] = s; pq[wv] = sq; }
  __syncthreads();
  s = ps[0] + ps[1] + ps[2] + ps[3];
  sq = pq[0] + pq[1] + pq[2] + pq[3];
  float mean = s * (1.f / DM);
  float rstd = rsqrtf(sq * (1.f / DM) - mean * mean + 1e-5f);
  y[tid] = (v0 - mean) * rstd * g[tid] + beta[tid];
  y[tid + 256] = (v1 - mean) * rstd * g[tid + 256] + beta[tid + 256];
}

__global__ __launch_bounds__(256) void zero_u32(unsigned* p) {
  if (threadIdx.x == 0) *p = 0u;
}

__global__ __launch_bounds__(256) void dec_mega(
    const int* __restrict__ tgt, const float* __restrict__ out_emb,
    const float* __restrict__ qkv1_w, const float* __restrict__ qkv1_b,
    const float* __restrict__ ln1_g, const float* __restrict__ ln1_b,
    const float* __restrict__ qkv2_w, const float* __restrict__ qkv2_b,
    const float* __restrict__ ln2_g, const float* __restrict__ ln2_b,
    const float* __restrict__ ffn1_w, const float* __restrict__ ffn1_b,
    const float* __restrict__ ffn2_w, const float* __restrict__ ffn2_b,
    const float* __restrict__ ln3_g, const float* __restrict__ ln3_b,
    const float* __restrict__ ow, const float* __restrict__ ob,
    const __bf16* __restrict__ kvb,
    float* __restrict__ dd, float* __restrict__ t1, float* __restrict__ qv,
    float* __restrict__ da, float* __restrict__ dh,
    unsigned* __restrict__ cnt, float* __restrict__ out) {
  __shared__ float red[4][64];
  __shared__ float q[64];
  __shared__ float sc[512];
  __shared__ float wred[4];

  int tid = threadIdx.x, blk = blockIdx.x;
  int gid = blk * 256 + tid;
  unsigned phase = 0;

  // embed (seq len 1): PE row 0 = (0,1,0,1,...)
  if (gid < NB * DM) {
    int b = gid >> 9, d = gid & 511;
    dd[gid] = out_emb[(size_t)tgt[b] * DM + d] * EMB_SCALE + ((d & 1) ? 1.f : 0.f);
  }
  gridbar(cnt, ++phase * DBLK);

  for (int i = 0; i < NL; ++i) {
    // ---- self-attn (S=1): out = dd @ Wv + bv ----
    {
      const float* Wv = qkv1_w + ((size_t)i * 3 + 2) * WQS_;
      const float* bv = qkv1_b + ((size_t)i * 3 + 2) * DM;
      int o = blk * 64 + (tid & 63);
      int b = o >> 9, c = o & 511, ks = tid >> 6;
      const float* ar = dd + b * 512;
      float a0 = 0.f, a1 = 0.f;
      for (int k = ks * 128; k < ks * 128 + 128; k += 2) {
        a0 += ar[k] * Wv[(size_t)k * 512 + c];
        a1 += ar[k + 1] * Wv[(size_t)(k + 1) * 512 + c];
      }
      red[ks][tid & 63] = a0 + a1;
      __syncthreads();
      if (tid < 64) {
        int o2 = blk * 64 + tid;
        t1[o2] = red[0][tid] + red[1][tid] + red[2][tid] + red[3][tid] +
                 bv[o2 & 511];
      }
    }
    gridbar(cnt, ++phase * DBLK);
    if (blk < NB)
      ln_row256(t1 + blk * 512, dd + blk * 512, ln1_g + i * DM, ln1_b + i * DM,
                dd + blk * 512);
    gridbar(cnt, ++phase * DBLK);

    // ---- cross-attn: q = dd @ Wq + bq ----
    {
      const float* Wq = qkv2_w + (size_t)i * 3 * WQS_;
      const float* bq = qkv2_b + (size_t)i * 3 * DM;
      int o = blk * 64 + (tid & 63);
      int b = o >> 9, c = o & 511, ks = tid >> 6;
      const float* ar = dd + b * 512;
      float a0 = 0.f, a1 = 0.f;
      for (int k = ks * 128; k < ks * 128 + 128; k += 2) {
        a0 += ar[k] * Wq[(size_t)k * 512 + c];
        a1 += ar[k + 1] * Wq[(size_t)(k + 1) * 512 + c];
      }
      red[ks][tid & 63] = a0 + a1;
      __syncthreads();
      if (tid < 64) {
        int o2 = blk * 64 + tid;
        qv[o2] = red[0][tid] + red[1][tid] + red[2][tid] + red[3][tid] +
                 bq[o2 & 511];
      }
    }
    gridbar(cnt, ++phase * DBLK);

    // ---- attention over 512 keys; block = (b,h) ----
    {
      int b = blk >> 3, h = blk & 7;
      int lane = tid & 63, wave = tid >> 6;
      const __bf16* Kb = kvb + (size_t)i * 2 * ACTL_;
      const __bf16* Vb = Kb + ACTL_;
      if (tid < 64) q[tid] = qv[b * 512 + h * 64 + tid];
      __syncthreads();
      for (int key = tid; key < 512; key += 256) {
        const __bf16* kp = &Kb[((size_t)b * 512 + key) * 512 + h * 64];
        float acc = 0.f;
#pragma unroll
        for (int k = 0; k < 64; k += 8) acc += dot8(*(const bf16x8*)&kp[k], &q[k]);
        sc[key] = acc * 0.125f;
      }
      __syncthreads();
      float m = -1e30f;
      for (int j = tid; j < 512; j += 256) m = fmaxf(m, sc[j]);
      for (int o = 32; o > 0; o >>= 1) m = fmaxf(m, __shfl_xor(m, o));
      if (lane == 0) wred[wave] = m;
      __syncthreads();
      m = fmaxf(fmaxf(wred[0], wred[1]), fmaxf(wred[2], wred[3]));
      float sum = 0.f;
      for (int j = tid; j < 512; j += 256) {
        float pv = __expf(sc[j] - m);
        sc[j] = pv;
        sum += pv;
      }
      for (int o = 32; o > 0; o >>= 1) sum += __shfl_xor(sum, o);
      __syncthreads();
      if (lane == 0) wred[wave] = sum;
      __syncthreads();
      float inv = 1.f / (wred[0] + wred[1] + wred[2] + wred[3]);
      int d = tid & 63, s4 = tid >> 6;
      float acc = 0.f;
      const __bf16* vp = &Vb[((size_t)b * 512 + s4 * 128) * 512 + h * 64 + d];
#pragma unroll 8
      for (int k = 0; k < 128; ++k) acc += sc[s4 * 128 + k] * (float)vp[(size_t)k * 512];
      red[s4][d] = acc;
      __syncthreads();
      if (tid < 64)
        da[b * 512 + h * 64 + tid] =
            (red[0][tid] + red[1][tid] + red[2][tid] + red[3][tid]) * inv;
    }
    gridbar(cnt, ++phase * DBLK);
    if (blk < NB)
      ln_row256(da + blk * 512, dd + blk * 512, ln2_g + i * DM, ln2_b + i * DM,
                dd + blk * 512);
    gridbar(cnt, ++phase * DBLK);

    // ---- ffn1: thread-per-output (8 x 2048) ----
    {
      const float* W1 = ffn1_w + (size_t)i * WFS_;
      int b = gid >> 11, c = gid & 2047;
      const float* ar = dd + b * 512;
      float a0 = 0.f, a1 = 0.f;
      for (int k = 0; k < 512; k += 2) {
        a0 += ar[k] * W1[(size_t)k * 2048 + c];
        a1 += ar[k + 1] * W1[(size_t)(k + 1) * 2048 + c];
      }
      dh[gid] = fmaxf(a0 + a1 + ffn1_b[i * DFF + c], 0.f);
    }
    gridbar(cnt, ++phase * DBLK);

    // ---- ffn2: 64 outputs/block, K=2048 split 4-way ----
    {
      const float* W2 = ffn2_w + (size_t)i * WFS_;
      int o = blk * 64 + (tid & 63);
      int b = o >> 9, c = o & 511, ks = tid >> 6;
      const float* hr = dh + b * 2048;
      float a0 = 0.f, a1 = 0.f;
      for (int k = ks * 512; k < ks * 512 + 512; k += 2) {
        a0 += hr[k] * W2[(size_t)k * 512 + c];
        a1 += hr[k + 1] * W2[(size_t)(k + 1) * 512 + c];
      }
      red[ks][tid & 63] = a0 + a1;
      __syncthreads();
      if (tid < 64) {
        int o2 = blk * 64 + tid;
        t1[o2] = red[0][tid] + red[1][tid] + red[2][tid] + red[3][tid] +
                 ffn2_b[i * DM + (o2 & 511)];
      }
    }
    gridbar(cnt, ++phase * DBLK);
    if (blk < NB)
      ln_row256(t1 + blk * 512, dd + blk * 512, ln3_g + i * DM, ln3_b + i * DM,
                dd + blk * 512);
    gridbar(cnt, ++phase * DBLK);
  }

  // ---- output projection: 8000 outputs, thread-per-output ----
  if (gid < NB * OUTD) {
    int b = gid / OUTD, c = gid - b * OUTD;
    const float* ar = dd + b * 512;
    float a0 = 0.f, a1 = 0.f;
    for (int k = 0; k < 512; k += 2) {
      a0 += ar[k] * ow[(size_t)k * OUTD + c];
      a1 += ar[k + 1] * ow[(size_t)(k + 1) * OUTD + c];
    }
    out[gid] = a0 + a1 + ob[c];
  }
}

// ---------------------------------------------------------------------------
extern "C" void kernel_launch(void* const* d_in, const int* in_sizes, int n_in,
                              void* d_out, int out_size, void* d_ws, size_t ws_size,
                              hipStream_t stream) {
  const int* x = (const int*)d_in[0];
  const int* target = (const int*)d_in[1];
  const float* in_emb = (const float*)d_in[2];
  const float* out_emb = (const float*)d_in[3];
  const float* enc_qkv_w = (const float*)d_in[4];
  const float* enc_qkv_b = (const float*)d_in[5];
  const float* enc_ln1_g = (const float*)d_in[6];
  const float* enc_ln1_b = (const float*)d_in[7];
  const float* enc_ffn1_w = (const float*)d_in[8];
  const float* enc_ffn1_b = (const float*)d_in[9];
  const float* enc_ffn2_w = (const float*)d_in[10];
  const float* enc_ffn2_b = (const float*)d_in[11];
  const float* enc_ln2_g = (const float*)d_in[12];
  const float* enc_ln2_b = (const float*)d_in[13];
  const float* dec_qkv1_w = (const float*)d_in[14];
  const float* dec_qkv1_b = (const float*)d_in[15];
  const float* dec_ln1_g = (const float*)d_in[16];
  const float* dec_ln1_b = (const float*)d_in[17];
  const float* dec_qkv2_w = (const float*)d_in[18];
  const float* dec_qkv2_b = (const float*)d_in[19];
  const float* dec_ln2_g = (const float*)d_in[20];
  const float* dec_ln2_b = (const float*)d_in[21];
  const float* dec_ffn1_w = (const float*)d_in[22];
  const float* dec_ffn1_b = (const float*)d_in[23];
  const float* dec_ffn2_w = (const float*)d_in[24];
  const float* dec_ffn2_b = (const float*)d_in[25];
  const float* dec_ln3_g = (const float*)d_in[26];
  const float* dec_ln3_b = (const float*)d_in[27];
  const float* out_w = (const float*)d_in[28];
  const float* out_b = (const float*)d_in[29];

  const long ACTL = (long)NB * SEQ * DM;           // 2M elems
  const int M = NB * SEQ;                           // 4096
  const long WQS = (long)DM * DM;
  const long WFS = (long)DM * DFF;

  char* p = (char*)d_ws;
  float* e = (float*)p;            p += ACTL * 4;
  float* tb = (float*)p;           p += ACTL * 4;
  float* dd = (float*)p;           p += NB * DM * 4;
  float* t1 = (float*)p;           p += NB * DM * 4;
  float* qv = (float*)p;           p += NB * DM * 4;
  float* da = (float*)p;           p += NB * DM * 4;
  float* dh = (float*)p;           p += NB * DFF * 4;
  unsigned* cnt = (unsigned*)p;    p += 256;
  p = (char*)(((uintptr_t)p + 255) & ~(uintptr_t)255);
  __bf16* eb = (__bf16*)p;         p += ACTL * 2;
  __bf16* qkvb = (__bf16*)p;       p += 3 * ACTL * 2;   // Q,K; slice 2 = V^T
  __bf16* hbb = (__bf16*)p;        p += (long)M * DFF * 2;
  __bf16* kvb = (__bf16*)p;        p += 12L * ACTL * 2; // [layer][K,V][4096][512]
  __bf16* wtq = (__bf16*)p;        p += 18L * WQS * 2;
  __bf16* wtf1 = (__bf16*)p;       p += 6L * WFS * 2;
  __bf16* wtf2 = (__bf16*)p;       p += 6L * WFS * 2;
  __bf16* wtd = (__bf16*)p;        p += 18L * WQS * 2;  // dec_qkv2^T (KV precompute)

  __bf16* vtb = qkvb + 2 * ACTL;

  // ---- one-time prep ----
  transpose_w<<<dim3(16, 16, 18), 256, 0, stream>>>(enc_qkv_w, wtq, DM, DM);
  transpose_w<<<dim3(64, 16, 6), 256, 0, stream>>>(enc_ffn1_w, wtf1, DM, DFF);
  transpose_w<<<dim3(16, 64, 6), 256, 0, stream>>>(enc_ffn2_w, wtf2, DFF, DM);
  transpose_w<<<dim3(16, 16, 18), 256, 0, stream>>>(dec_qkv2_w, wtd, DM, DM);
  zero_u32<<<1, 256, 0, stream>>>(cnt);

  // ---- encoder ----
  embed_enc<<<(M * DM) / 256, 256, 0, stream>>>(x, in_emb, e, eb);
  for (int i = 0; i < NL; ++i) {
    mfma_gemm<128, false, false, true, true, false><<<dim3(4, 32, 3), 256, 0, stream>>>(
        eb, wtq + (size_t)i * 3 * WQS, enc_qkv_b + (size_t)i * 3 * DM,
        nullptr, qkvb, vtb, M, DM, DM, WQS, DM, ACTL);
    attn_mfma<<<dim3(SEQ / 16, NB * NH), 256, 0, stream>>>(qkvb, vtb, tb);
    add_ln<true><<<M, 256, 0, stream>>>(tb, e, enc_ln1_g + i * DM,
                                        enc_ln1_b + i * DM, e, eb);
    mfma_gemm<128, true, false, true, false, false><<<dim3(16, 32, 1), 256, 0, stream>>>(
        eb, wtf1 + (size_t)i * WFS, enc_ffn1_b + (size_t)i * DFF,
        nullptr, hbb, nullptr, M, DFF, DM, 0, 0, 0);
    mfma_gemm<64, false, true, false, false, false><<<dim3(8, 32, 1), 256, 0, stream>>>(
        hbb, wtf2 + (size_t)i * WFS, enc_ffn2_b + (size_t)i * DM,
        tb, nullptr, nullptr, M, DM, DFF, 0, 0, 0);
    add_ln<true><<<M, 256, 0, stream>>>(tb, e, enc_ln2_g + i * DM,
                                        enc_ln2_b + i * DM, e, eb);
  }

  // ---- cross K/V for all 6 layers in one dispatch (bf16 out) ----
  mfma_gemm<128, false, false, true, false, true><<<dim3(4, 32, 12), 256, 0, stream>>>(
      eb, wtd, dec_qkv2_b, nullptr, kvb, nullptr, M, DM, DM, WQS, DM, ACTL);

  // ---- decoder: one persistent kernel, manual grid barriers ----
  dec_mega<<<DBLK, 256, 0, stream>>>(
      target, out_emb, dec_qkv1_w, dec_qkv1_b, dec_ln1_g, dec_ln1_b,
      dec_qkv2_w, dec_qkv2_b, dec_ln2_g, dec_ln2_b, dec_ffn1_w, dec_ffn1_b,
      dec_ffn2_w, dec_ffn2_b, dec_ln3_g, dec_ln3_b, out_w, out_b, kvb,
      dd, t1, qv, da, dh, cnt, (float*)d_out);
}